// Round 5
// baseline (5604.595 us; speedup 1.0000x reference)
//
#include <hip/hip_runtime.h>
#include <hip/hip_bf16.h>

typedef unsigned short u16;
typedef unsigned int u32;

#define HD 512
#define BATCH 128
#define TENC 512
#define WPAD 520   // LDS row stride in bf16 elems (even -> u32-aligned rows)

typedef float f32x4 __attribute__((ext_vector_type(4)));
typedef short s16x8 __attribute__((ext_vector_type(8)));

__device__ __forceinline__ u16 f2b(float f) {
    u32 u = __float_as_uint(f);
    u32 r = (u + 0x7FFFu + ((u >> 16) & 1u)) >> 16;   // RNE
    return (u16)r;
}
__device__ __forceinline__ float b2f(u16 h) {
    return __uint_as_float(((u32)h) << 16);
}
__device__ __forceinline__ float sigm(float z) { return 1.0f / (1.0f + __expf(-z)); }
__device__ __forceinline__ float tanh_f(float z) { return 1.0f - 2.0f / (__expf(2.0f * z) + 1.0f); }

__device__ __forceinline__ u32 cld(const u32* p) {
    return __hip_atomic_load(p, __ATOMIC_RELAXED, __HIP_MEMORY_SCOPE_AGENT);
}
__device__ __forceinline__ void cst(u32* p, u32 v) {
    __hip_atomic_store(p, v, __ATOMIC_RELAXED, __HIP_MEMORY_SCOPE_AGENT);
}
// packed banded bf16 pair check: both halves in [lo,hi] (u16 unsigned cmp).
// even step band +2 -> bits [0x3F80,0x4040]; odd band -2 -> [0xBF80,0xC040].
// poison 0xAAAA / zeros / opposite parity all fail.
__device__ __forceinline__ bool okw(u32 v, u32 lo, u32 hi) {
    u32 a = v & 0xFFFFu, b = v >> 16;
    return a >= lo && a <= hi && b >= lo && b <= hi;
}

// ---------------------------------------------------------------------------
// init: seed encoder ring slot 0 with packed bf16(h0+2)
// ---------------------------------------------------------------------------
__global__ void init_misc(const float* __restrict__ h0, u32* __restrict__ hbT) {
    int w = blockIdx.x * 256 + threadIdx.x;        // 128 blocks x 256 = 32768 words
    if (w < 32768) {
        int g = w >> 12, b = (w >> 8) & 15, jp = w & 255;
        int base = (g * 16 + b) * 512 + jp * 2;
        u32 lo = f2b(h0[base] + 2.0f);
        u32 hi = f2b(h0[base + 1] + 2.0f);
        hbT[(size_t)g * 4096 + b * 256 + jp + ((size_t)0) ] = lo | (hi << 16);
    }
}

// ---------------------------------------------------------------------------
// Encoder LSTM: 8 batch-groups x 16 wgs, Whh register-resident.
// Handoff: packed banded-bf16 pairs, fire-and-forget write-through stores;
// readers do PARALLEL-ROUND polling (batch load, check all, re-issue missing
// together) -- one IF$ latency per round, data doubles as its own flag.
// ---------------------------------------------------------------------------
__global__ __launch_bounds__(512, 2) void enc_lstm(
    const float* __restrict__ xseq, const float* __restrict__ c0,
    const float* __restrict__ Wih, const float* __restrict__ Whh,
    const float* __restrict__ bih, const float* __restrict__ bhh,
    u32* __restrict__ enc32, u32* __restrict__ hbT) {

    __shared__ u16 hlds[16 * WPAD];     // staged h tile [16 b][512 k] bf16
    __shared__ float exg[16 * 132];     // gate pre-activations [b][128 rows]
    __shared__ float bias_l[128];
    __shared__ float wih_l[128];

    const int tid = threadIdx.x;
    const int g = blockIdx.x & 7;       // batch group
    const int sl = blockIdx.x >> 3;     // hidden slot 0..15

    if (tid < 128) {
        int n = (tid >> 5) * 512 + sl * 32 + (tid & 31);
        bias_l[tid] = bih[n] + bhh[n];
        wih_l[tid] = Wih[n];
    }

    const int bT = tid >> 5, jl = tid & 31;               // cell-update mapping
    float c = c0[(g * 16 + bT) * HD + sl * 32 + jl];      // persistent cell state

    const int lane = tid & 63, wv = tid >> 6;
    const int q = lane >> 4, cl = lane & 15;
    const int R = (wv >> 1) * 32 + (wv & 1) * 16;         // wave's 16 gate-rows

    // this lane's 16 B-fragments of Whh in registers (64 VGPRs)
    s16x8 bw[16];
    {
        int r = R + cl;
        int grow = (r >> 5) * 512 + sl * 32 + (r & 31);
        const float* wrow = Whh + (size_t)grow * 512;
        #pragma unroll
        for (int ks = 0; ks < 16; ++ks) {
            s16x8 v;
            #pragma unroll
            for (int j = 0; j < 8; ++j)
                v[j] = (short)f2b(wrow[ks * 32 + q * 8 + j]);
            bw[ks] = v;
        }
    }
    u32* hlds32 = (u32*)hlds;
    __syncthreads();

    for (int t = 0; t < TENC; ++t) {
        // ---- poll h_t (8 packed words/thread), parallel retry rounds
        const u32* src = hbT + (size_t)((t % 3) * 8 + g) * 4096;
        const u32 blo = (t & 1) ? 0xBF80u : 0x3F80u;
        const u32 bhi = (t & 1) ? 0xC040u : 0x4040u;
        const float band = (t & 1) ? -2.0f : 2.0f;
        u32 v[8];
        #pragma unroll
        for (int i = 0; i < 8; ++i) v[i] = cld(src + tid + i * 512);
        for (;;) {
            u32 bad = 0;
            #pragma unroll
            for (int i = 0; i < 8; ++i) bad |= (okw(v[i], blo, bhi) ? 0u : (1u << i));
            if (!bad) break;
            __builtin_amdgcn_s_sleep(1);
            #pragma unroll
            for (int i = 0; i < 8; ++i)
                if (bad & (1u << i)) v[i] = cld(src + tid + i * 512);
        }
        #pragma unroll
        for (int i = 0; i < 8; ++i) {
            int idx = tid + i * 512;
            int b = idx >> 8, w = idx & 255;
            float f0 = b2f((u16)(v[i] & 0xFFFF)) - band;    // exact on 2^-8 grid
            float f1 = b2f((u16)(v[i] >> 16)) - band;
            u32 pk = (__float_as_uint(f0) >> 16) | (__float_as_uint(f1) & 0xFFFF0000u);
            hlds32[b * 260 + w] = pk;
        }
        float xv = xseq[t * BATCH + g * 16 + bT];
        __syncthreads();

        // ---- MFMA: gates[b][R+cl] over K=512
        f32x4 acc = {0.f, 0.f, 0.f, 0.f};
        #pragma unroll
        for (int ks = 0; ks < 16; ++ks) {
            s16x8 av = *(const s16x8*)&hlds[cl * WPAD + ks * 32 + q * 8];
            acc = __builtin_amdgcn_mfma_f32_16x16x32_bf16(av, bw[ks], acc, 0, 0, 0);
        }
        #pragma unroll
        for (int r4 = 0; r4 < 4; ++r4)
            exg[(q * 4 + r4) * 132 + R + cl] = acc[r4];
        __syncthreads();

        // ---- LSTM cell for (bT, jl)
        const float* exb = &exg[bT * 132];
        float gi = exb[jl]      + xv * wih_l[jl]      + bias_l[jl];
        float gf = exb[32 + jl] + xv * wih_l[32 + jl] + bias_l[32 + jl];
        float gg = exb[64 + jl] + xv * wih_l[64 + jl] + bias_l[64 + jl];
        float go = exb[96 + jl] + xv * wih_l[96 + jl] + bias_l[96 + jl];
        c = sigm(gf) * c + sigm(gi) * tanh_f(gg);
        float hv = sigm(go) * tanh_f(c);
        int jgl = sl * 32 + jl;

        // ---- pack raw + banded pairs, fire-and-forget stores
        const float band2 = ((t + 1) & 1) ? -2.0f : 2.0f;
        u16 rb = f2b(hv);
        u16 bb = f2b(hv + band2);
        u32 both = ((u32)bb << 16) | (u32)rb;
        u32 nb = (u32)__shfl_down((int)both, 1, 64);
        if (!(jl & 1)) {
            u32 rawpair = (u32)rb | ((nb & 0xFFFFu) << 16);
            u32 bandpair = (u32)bb | (nb & 0xFFFF0000u);
            enc32[(((size_t)t * BATCH + g * 16 + bT) * HD + jgl) >> 1] = rawpair;
            cst(hbT + (size_t)(((t + 1) % 3) * 8 + g) * 4096 + bT * 256 + (jgl >> 1),
                bandpair);
        }
    }
}

// ---------------------------------------------------------------------------
// Fused decoder, one dispatch, 132 wgs:
//   wg 0..3   : RNN wgs (rWhh register-resident, 128 j-rows each).
//   wg 4..131 : attention wg per batch row b. enc slice (512 KB) cached in
//               VGPRs ONCE (64 x uint4 per lane) -> zero enc traffic per step.
// Handoff: packed banded-bf16 h ring (depth 3), f32-banded per-step x slots.
// ---------------------------------------------------------------------------
__global__ __launch_bounds__(512, 1) void dec_all(
    const float* __restrict__ xlast, const u16* __restrict__ enc,
    const float* __restrict__ rWhh, const float* __restrict__ rWih,
    const float* __restrict__ rbih, const float* __restrict__ rbhh,
    const float* __restrict__ linW, const float* __restrict__ linb,
    float* __restrict__ dout, u32* __restrict__ hh, u32* __restrict__ xb) {

    __shared__ union {
        struct {
            u16 hlds[128 * WPAD];      // 133120 B: h_s bf16 [128 b][512 k]
            float xl[128];
            float wihl[128];
            float biasl[128];
        } r;
        struct {
            float hn[512];
            float ctxl[8 * 512];
            float red[512];
            float mw[8], lw[8];
        } a;
    } sm;

    const int tid = threadIdx.x;
    const int wg = blockIdx.x;
    const int lane = tid & 63, wv = tid >> 6;

    if (wg < 4) {
        // ================= RNN workgroup =================
        const int q = lane >> 4, cl = lane & 15;
        const int R = (wv >> 1) * 32 + (wv & 1) * 16;
        const int jbase = wg * 128;
        u32* hlds32 = (u32*)sm.r.hlds;

        if (tid < 128) {
            sm.r.wihl[tid] = rWih[jbase + tid];
            sm.r.biasl[tid] = rbih[jbase + tid] + rbhh[jbase + tid];
        }
        s16x8 bw[16];
        {
            const float* wrow = rWhh + (size_t)(jbase + R + cl) * 512;
            #pragma unroll
            for (int ks = 0; ks < 16; ++ks) {
                s16x8 v;
                #pragma unroll
                for (int j = 0; j < 8; ++j)
                    v[j] = (short)f2b(wrow[ks * 32 + q * 8 + j]);
                bw[ks] = v;
            }
        }
        __syncthreads();

        for (int s = 0; s < 32; ++s) {
            // ---- stage h_s into LDS bf16-packed [128 b][512 k]
            if (s == 0) {
                const u32* h0p = (const u32*)(enc + (size_t)511 * BATCH * HD);
                for (int i = 0; i < 64; ++i) {
                    int idx = tid + i * 512;
                    hlds32[(idx >> 8) * 260 + (idx & 255)] = h0p[idx];
                }
            } else {
                const u32* src = hh + (size_t)(s % 3) * 32768;
                const u32 blo = (s & 1) ? 0xBF80u : 0x3F80u;
                const u32 bhi = (s & 1) ? 0xC040u : 0x4040u;
                const float band = (s & 1) ? -2.0f : 2.0f;
                #pragma unroll
                for (int ch = 0; ch < 4; ++ch) {
                    u32 v[16];
                    #pragma unroll
                    for (int i = 0; i < 16; ++i)
                        v[i] = cld(src + tid + (ch * 16 + i) * 512);
                    for (;;) {
                        u32 bad = 0;
                        #pragma unroll
                        for (int i = 0; i < 16; ++i)
                            bad |= (okw(v[i], blo, bhi) ? 0u : (1u << i));
                        if (!bad) break;
                        __builtin_amdgcn_s_sleep(1);
                        #pragma unroll
                        for (int i = 0; i < 16; ++i)
                            if (bad & (1u << i)) v[i] = cld(src + tid + (ch * 16 + i) * 512);
                    }
                    #pragma unroll
                    for (int i = 0; i < 16; ++i) {
                        int idx = tid + (ch * 16 + i) * 512;
                        float f0 = b2f((u16)(v[i] & 0xFFFF)) - band;
                        float f1 = b2f((u16)(v[i] >> 16)) - band;
                        u32 pk = (__float_as_uint(f0) >> 16) |
                                 (__float_as_uint(f1) & 0xFFFF0000u);
                        hlds32[(idx >> 8) * 260 + (idx & 255)] = pk;
                    }
                }
            }
            __syncthreads();

            // ---- GEMM: a[b][j] = h_s @ Whh^T (overlaps att step s-1)
            f32x4 acc[8];
            #pragma unroll
            for (int mt = 0; mt < 8; ++mt) acc[mt] = (f32x4){0.f, 0.f, 0.f, 0.f};
            #pragma unroll
            for (int ks = 0; ks < 16; ++ks) {
                s16x8 bv = bw[ks];
                #pragma unroll
                for (int mt = 0; mt < 8; ++mt) {
                    s16x8 av = *(const s16x8*)
                        &sm.r.hlds[(mt * 16 + cl) * WPAD + ks * 32 + q * 8];
                    acc[mt] = __builtin_amdgcn_mfma_f32_16x16x32_bf16(av, bv, acc[mt], 0, 0, 0);
                }
            }

            // ---- poll x_s (f32 banded, unique slot per step)
            if (s == 0) {
                if (tid < 128) sm.r.xl[tid] = xlast[tid];
            } else if (tid < 128) {
                u32 v = cld(xb + s * 128 + tid);
                float f = __uint_as_float(v);
                while (!(f >= 2.0f && f < 3e38f)) {
                    __builtin_amdgcn_s_sleep(1);
                    v = cld(xb + s * 128 + tid);
                    f = __uint_as_float(v);
                }
                sm.r.xl[tid] = f - 2.0f;
            }
            __syncthreads();

            // ---- h_{s+1} = tanh(a + x*wih + bias), banded-pair store to ring
            const int m1 = s + 1;
            u32* dst = hh + (size_t)(m1 % 3) * 32768;
            const float bandw = (m1 & 1) ? -2.0f : 2.0f;
            const int jloc = R + cl;
            const float wihj = sm.r.wihl[jloc];
            const float biaj = sm.r.biasl[jloc];
            #pragma unroll
            for (int mt = 0; mt < 8; ++mt) {
                #pragma unroll
                for (int r4 = 0; r4 < 4; ++r4) {
                    int b = mt * 16 + q * 4 + r4;
                    float hvv = tanh_f(acc[mt][r4] + sm.r.xl[b] * wihj + biaj);
                    u16 bb = f2b(hvv + bandw);
                    u32 nb = (u32)__shfl_down((int)(u32)bb, 1, 64);
                    if (!(cl & 1))
                        cst(dst + b * 256 + ((jbase + jloc) >> 1),
                            (u32)bb | (nb << 16));
                }
            }
            __syncthreads();
        }
    } else {
        // ================= attention workgroup (one batch row) =================
        const int b = wg - 4;
        const float lwt = linW[tid];
        const float lb = linb[0];
        const u16* eb = enc + (size_t)b * HD + lane * 8;

        // ---- one-time enc slice cache: 64 t-rows x 16B per lane (256 VGPRs)
        uint4 ec[64];
        #pragma unroll
        for (int i = 0; i < 64; ++i)
            ec[i] = *(const uint4*)(eb + (size_t)(i * 8 + wv) * 65536);

        for (int s = 0; s < 32; ++s) {
            // ---- poll h_{s+1} (256 packed words, tid<256)
            {
                const int m1 = s + 1;
                const u32* src = hh + (size_t)(m1 % 3) * 32768 + b * 256;
                const u32 blo = (m1 & 1) ? 0xBF80u : 0x3F80u;
                const u32 bhi = (m1 & 1) ? 0xC040u : 0x4040u;
                const float band = (m1 & 1) ? -2.0f : 2.0f;
                if (tid < 256) {
                    u32 v = cld(src + tid);
                    while (!okw(v, blo, bhi)) {
                        __builtin_amdgcn_s_sleep(1);
                        v = cld(src + tid);
                    }
                    sm.a.hn[2 * tid]     = b2f((u16)(v & 0xFFFF)) - band;
                    sm.a.hn[2 * tid + 1] = b2f((u16)(v >> 16)) - band;
                }
            }
            __syncthreads();

            float h8[8];
            #pragma unroll
            for (int i = 0; i < 8; ++i) h8[i] = sm.a.hn[lane * 8 + i];

            // ---- online-softmax attention from the register cache
            float m = -1e30f, l = 0.f;
            float acc[8] = {0, 0, 0, 0, 0, 0, 0, 0};
            #pragma unroll
            for (int blk = 0; blk < 8; ++blk) {
                float sp[8];
                #pragma unroll
                for (int i = 0; i < 8; ++i) {
                    uint4 e4 = ec[blk * 8 + i];
                    float d = 0.f;
                    d = fmaf(b2f((u16)(e4.x & 0xFFFF)), h8[0], d);
                    d = fmaf(b2f((u16)(e4.x >> 16)),    h8[1], d);
                    d = fmaf(b2f((u16)(e4.y & 0xFFFF)), h8[2], d);
                    d = fmaf(b2f((u16)(e4.y >> 16)),    h8[3], d);
                    d = fmaf(b2f((u16)(e4.z & 0xFFFF)), h8[4], d);
                    d = fmaf(b2f((u16)(e4.z >> 16)),    h8[5], d);
                    d = fmaf(b2f((u16)(e4.w & 0xFFFF)), h8[6], d);
                    d = fmaf(b2f((u16)(e4.w >> 16)),    h8[7], d);
                    sp[i] = d;
                }
                #pragma unroll
                for (int mk = 1; mk < 64; mk <<= 1) {
                    #pragma unroll
                    for (int i = 0; i < 8; ++i) sp[i] += __shfl_xor(sp[i], mk, 64);
                }
                float bm = sp[0];
                #pragma unroll
                for (int i = 1; i < 8; ++i) bm = fmaxf(bm, sp[i]);
                float nm = fmaxf(m, bm);
                float sc = __expf(m - nm);
                l *= sc;
                #pragma unroll
                for (int j = 0; j < 8; ++j) acc[j] *= sc;
                #pragma unroll
                for (int i = 0; i < 8; ++i) {
                    float p = __expf(sp[i] - nm);
                    l += p;
                    uint4 e4 = ec[blk * 8 + i];
                    acc[0] = fmaf(p, b2f((u16)(e4.x & 0xFFFF)), acc[0]);
                    acc[1] = fmaf(p, b2f((u16)(e4.x >> 16)),    acc[1]);
                    acc[2] = fmaf(p, b2f((u16)(e4.y & 0xFFFF)), acc[2]);
                    acc[3] = fmaf(p, b2f((u16)(e4.y >> 16)),    acc[3]);
                    acc[4] = fmaf(p, b2f((u16)(e4.z & 0xFFFF)), acc[4]);
                    acc[5] = fmaf(p, b2f((u16)(e4.z >> 16)),    acc[5]);
                    acc[6] = fmaf(p, b2f((u16)(e4.w & 0xFFFF)), acc[6]);
                    acc[7] = fmaf(p, b2f((u16)(e4.w >> 16)),    acc[7]);
                }
                m = nm;
            }
            if (lane == 0) { sm.a.mw[wv] = m; sm.a.lw[wv] = l; }
            #pragma unroll
            for (int i = 0; i < 8; ++i) sm.a.ctxl[wv * HD + lane * 8 + i] = acc[i];
            __syncthreads();

            // ---- merge waves, project, relu, emit out + x
            float M = sm.a.mw[0];
            #pragma unroll
            for (int i = 1; i < 8; ++i) M = fmaxf(M, sm.a.mw[i]);
            float L = 0.f, aw[8];
            #pragma unroll
            for (int i = 0; i < 8; ++i) {
                aw[i] = __expf(sm.a.mw[i] - M);
                L += aw[i] * sm.a.lw[i];
            }
            float cj = 0.f;
            #pragma unroll
            for (int i = 0; i < 8; ++i) cj = fmaf(aw[i], sm.a.ctxl[i * HD + tid], cj);
            float r = cj * lwt;
            #pragma unroll
            for (int mk = 1; mk < 64; mk <<= 1) r += __shfl_xor(r, mk, 64);
            if (lane == 0) sm.a.red[wv] = r;
            __syncthreads();
            if (tid == 0) {
                float o = (sm.a.red[0] + sm.a.red[1] + sm.a.red[2] + sm.a.red[3] +
                           sm.a.red[4] + sm.a.red[5] + sm.a.red[6] + sm.a.red[7]) / L + lb;
                o = fmaxf(o, 0.f);
                dout[s * BATCH + b] = o;
                if (s < 31)
                    cst(xb + (s + 1) * 128 + b, __float_as_uint(o + 2.0f));
            }
            __syncthreads();
        }
    }
}

// ---------------------------------------------------------------------------
extern "C" void kernel_launch(void* const* d_in, const int* in_sizes, int n_in,
                              void* d_out, int out_size, void* d_ws, size_t ws_size,
                              hipStream_t stream) {
    const float* xseq = (const float*)d_in[0];   // [513,128,1]
    const float* h0   = (const float*)d_in[1];
    const float* c0   = (const float*)d_in[2];
    const float* Wih  = (const float*)d_in[3];   // [2048,1]
    const float* Whh  = (const float*)d_in[4];   // [2048,512]
    const float* bih  = (const float*)d_in[5];
    const float* bhh  = (const float*)d_in[6];
    const float* rWih = (const float*)d_in[7];   // [512,1]
    const float* rWhh = (const float*)d_in[8];   // [512,512]
    const float* rbih = (const float*)d_in[9];
    const float* rbhh = (const float*)d_in[10];
    const float* linW = (const float*)d_in[11];  // [1,512]
    const float* linb = (const float*)d_in[12];
    float* dout = (float*)d_out;                 // [32,128,1]

    // workspace layout (~64.8 MB)
    char* ws = (char*)d_ws;
    u16* enc = (u16*)ws;                         // 64 MB bf16 [t][b][h]
    u32* hbT = (u32*)(ws + 67108864);            // enc ring: 3 x 8 x 4096 u32 (384 KB)
    u32* hh  = (u32*)(ws + 67502080);            // dec h ring: 3 x 32768 u32 (384 KB)
    u32* xb  = (u32*)(ws + 67895296);            // dec x: 32 x 128 f32 (16 KB)

    init_misc<<<128, 256, 0, stream>>>(h0, hbT);
    enc_lstm<<<128, 512, 0, stream>>>(xseq, c0, Wih, Whh, bih, bhh,
                                      (u32*)enc, hbT);
    dec_all<<<132, 512, 0, stream>>>(xseq + 512 * BATCH, enc, rWhh, rWih,
                                     rbih, rbhh, linW, linb, dout, hh, xb);
}

// Round 6
// 5473.236 us; speedup vs baseline: 1.0240x; 1.0240x over previous
//
#include <hip/hip_runtime.h>
#include <hip/hip_bf16.h>

typedef unsigned short u16;
typedef unsigned int u32;

#define HD 512
#define BATCH 128
#define TENC 512
#define WPAD 520   // LDS row stride in bf16 elems (even -> u32-aligned rows)

typedef float f32x4 __attribute__((ext_vector_type(4)));
typedef short s16x8 __attribute__((ext_vector_type(8)));

__device__ __forceinline__ u16 f2b(float f) {
    u32 u = __float_as_uint(f);
    u32 r = (u + 0x7FFFu + ((u >> 16) & 1u)) >> 16;   // RNE
    return (u16)r;
}
__device__ __forceinline__ float b2f(u16 h) {
    return __uint_as_float(((u32)h) << 16);
}
__device__ __forceinline__ float sigm(float z) { return 1.0f / (1.0f + __expf(-z)); }
__device__ __forceinline__ float tanh_f(float z) { return 1.0f - 2.0f / (__expf(2.0f * z) + 1.0f); }

__device__ __forceinline__ u32 cld(const u32* p) {
    return __hip_atomic_load(p, __ATOMIC_RELAXED, __HIP_MEMORY_SCOPE_AGENT);
}
__device__ __forceinline__ void cst(u32* p, u32 v) {
    __hip_atomic_store(p, v, __ATOMIC_RELAXED, __HIP_MEMORY_SCOPE_AGENT);
}
// packed banded bf16 pair check: both halves in [lo,hi] (u16 unsigned cmp).
// even step band +2 -> bits [0x3F80,0x4040]; odd band -2 -> [0xBF80,0xC040].
__device__ __forceinline__ bool okw(u32 v, u32 lo, u32 hi) {
    u32 a = v & 0xFFFFu, b = v >> 16;
    return a >= lo && a <= hi && b >= lo && b <= hi;
}

// ---------------------------------------------------------------------------
// init: seed encoder ring slot 0 with packed bf16(h0+2)
// ---------------------------------------------------------------------------
__global__ void init_misc(const float* __restrict__ h0, u32* __restrict__ hbT) {
    int w = blockIdx.x * 256 + threadIdx.x;        // 128 blocks x 256 = 32768 words
    if (w < 32768) {
        int g = w >> 12, b = (w >> 8) & 15, jp = w & 255;
        int base = (g * 16 + b) * 512 + jp * 2;
        u32 lo = f2b(h0[base] + 2.0f);
        u32 hi = f2b(h0[base + 1] + 2.0f);
        hbT[(size_t)g * 4096 + b * 256 + jp] = lo | (hi << 16);
    }
}

// ---------------------------------------------------------------------------
// Encoder LSTM (unchanged from round 5): 8 batch-groups x 16 wgs, Whh
// register-resident; packed banded-bf16 handoff + parallel-round polling.
// ---------------------------------------------------------------------------
__global__ __launch_bounds__(512, 2) void enc_lstm(
    const float* __restrict__ xseq, const float* __restrict__ c0,
    const float* __restrict__ Wih, const float* __restrict__ Whh,
    const float* __restrict__ bih, const float* __restrict__ bhh,
    u32* __restrict__ enc32, u32* __restrict__ hbT) {

    __shared__ u16 hlds[16 * WPAD];
    __shared__ float exg[16 * 132];
    __shared__ float bias_l[128];
    __shared__ float wih_l[128];

    const int tid = threadIdx.x;
    const int g = blockIdx.x & 7;
    const int sl = blockIdx.x >> 3;

    if (tid < 128) {
        int n = (tid >> 5) * 512 + sl * 32 + (tid & 31);
        bias_l[tid] = bih[n] + bhh[n];
        wih_l[tid] = Wih[n];
    }

    const int bT = tid >> 5, jl = tid & 31;
    float c = c0[(g * 16 + bT) * HD + sl * 32 + jl];

    const int lane = tid & 63, wv = tid >> 6;
    const int q = lane >> 4, cl = lane & 15;
    const int R = (wv >> 1) * 32 + (wv & 1) * 16;

    s16x8 bw[16];
    {
        int r = R + cl;
        int grow = (r >> 5) * 512 + sl * 32 + (r & 31);
        const float* wrow = Whh + (size_t)grow * 512;
        #pragma unroll
        for (int ks = 0; ks < 16; ++ks) {
            s16x8 v;
            #pragma unroll
            for (int j = 0; j < 8; ++j)
                v[j] = (short)f2b(wrow[ks * 32 + q * 8 + j]);
            bw[ks] = v;
        }
    }
    u32* hlds32 = (u32*)hlds;
    __syncthreads();

    for (int t = 0; t < TENC; ++t) {
        const u32* src = hbT + (size_t)((t % 3) * 8 + g) * 4096;
        const u32 blo = (t & 1) ? 0xBF80u : 0x3F80u;
        const u32 bhi = (t & 1) ? 0xC040u : 0x4040u;
        const float band = (t & 1) ? -2.0f : 2.0f;
        u32 v[8];
        #pragma unroll
        for (int i = 0; i < 8; ++i) v[i] = cld(src + tid + i * 512);
        for (;;) {
            u32 bad = 0;
            #pragma unroll
            for (int i = 0; i < 8; ++i) bad |= (okw(v[i], blo, bhi) ? 0u : (1u << i));
            if (!bad) break;
            __builtin_amdgcn_s_sleep(1);
            #pragma unroll
            for (int i = 0; i < 8; ++i)
                if (bad & (1u << i)) v[i] = cld(src + tid + i * 512);
        }
        #pragma unroll
        for (int i = 0; i < 8; ++i) {
            int idx = tid + i * 512;
            int b = idx >> 8, w = idx & 255;
            float f0 = b2f((u16)(v[i] & 0xFFFF)) - band;
            float f1 = b2f((u16)(v[i] >> 16)) - band;
            u32 pk = (__float_as_uint(f0) >> 16) | (__float_as_uint(f1) & 0xFFFF0000u);
            hlds32[b * 260 + w] = pk;
        }
        float xv = xseq[t * BATCH + g * 16 + bT];
        __syncthreads();

        f32x4 acc = {0.f, 0.f, 0.f, 0.f};
        #pragma unroll
        for (int ks = 0; ks < 16; ++ks) {
            s16x8 av = *(const s16x8*)&hlds[cl * WPAD + ks * 32 + q * 8];
            acc = __builtin_amdgcn_mfma_f32_16x16x32_bf16(av, bw[ks], acc, 0, 0, 0);
        }
        #pragma unroll
        for (int r4 = 0; r4 < 4; ++r4)
            exg[(q * 4 + r4) * 132 + R + cl] = acc[r4];
        __syncthreads();

        const float* exb = &exg[bT * 132];
        float gi = exb[jl]      + xv * wih_l[jl]      + bias_l[jl];
        float gf = exb[32 + jl] + xv * wih_l[32 + jl] + bias_l[32 + jl];
        float gg = exb[64 + jl] + xv * wih_l[64 + jl] + bias_l[64 + jl];
        float go = exb[96 + jl] + xv * wih_l[96 + jl] + bias_l[96 + jl];
        c = sigm(gf) * c + sigm(gi) * tanh_f(gg);
        float hv = sigm(go) * tanh_f(c);
        int jgl = sl * 32 + jl;

        const float band2 = ((t + 1) & 1) ? -2.0f : 2.0f;
        u16 rb = f2b(hv);
        u16 bb = f2b(hv + band2);
        u32 both = ((u32)bb << 16) | (u32)rb;
        u32 nb = (u32)__shfl_down((int)both, 1, 64);
        if (!(jl & 1)) {
            u32 rawpair = (u32)rb | ((nb & 0xFFFFu) << 16);
            u32 bandpair = (u32)bb | (nb & 0xFFFF0000u);
            enc32[(((size_t)t * BATCH + g * 16 + bT) * HD + jgl) >> 1] = rawpair;
            cst(hbT + (size_t)(((t + 1) % 3) * 8 + g) * 4096 + bT * 256 + (jgl >> 1),
                bandpair);
        }
    }
}

// ---------------------------------------------------------------------------
// Fused decoder, 132 wgs: wg 0..3 RNN (register-resident rWhh), wg 4..131
// attention (one per batch row). Att enc-slice is 3-tier cached:
//   tt in [0,24)  -> 24 uint4 in VGPRs (96 regs, fits 256 cap @ 2 waves/SIMD)
//   tt in [24,40) -> 128 KB LDS (wave-private rows, no barrier needed)
//   tt in [40,64) -> streamed 192 KB/step; 16wg x 192KB = 3MB <= 4MB L2/XCD
//                    -> L2-resident after step 0.
// ---------------------------------------------------------------------------
__global__ __launch_bounds__(512, 2) void dec_all(
    const float* __restrict__ xlast, const u16* __restrict__ enc,
    const float* __restrict__ rWhh, const float* __restrict__ rWih,
    const float* __restrict__ rbih, const float* __restrict__ rbhh,
    const float* __restrict__ linW, const float* __restrict__ linb,
    float* __restrict__ dout, u32* __restrict__ hh, u32* __restrict__ xb) {

    __shared__ union {
        struct {
            u16 hlds[128 * WPAD];      // 133120 B
            float xl[128];
            float wihl[128];
            float biasl[128];
        } r;
        struct {
            u16 elds[128 * 512];       // 131072 B enc LDS tier
            float hn[512];
            float ctxl[8 * 512];
            float red[512];
            float mw[8], lw[8];
        } a;
    } sm;

    const int tid = threadIdx.x;
    const int wg = blockIdx.x;
    const int lane = tid & 63, wv = tid >> 6;

    if (wg < 4) {
        // ================= RNN workgroup (unchanged) =================
        const int q = lane >> 4, cl = lane & 15;
        const int R = (wv >> 1) * 32 + (wv & 1) * 16;
        const int jbase = wg * 128;
        u32* hlds32 = (u32*)sm.r.hlds;

        if (tid < 128) {
            sm.r.wihl[tid] = rWih[jbase + tid];
            sm.r.biasl[tid] = rbih[jbase + tid] + rbhh[jbase + tid];
        }
        s16x8 bw[16];
        {
            const float* wrow = rWhh + (size_t)(jbase + R + cl) * 512;
            #pragma unroll
            for (int ks = 0; ks < 16; ++ks) {
                s16x8 v;
                #pragma unroll
                for (int j = 0; j < 8; ++j)
                    v[j] = (short)f2b(wrow[ks * 32 + q * 8 + j]);
                bw[ks] = v;
            }
        }
        __syncthreads();

        for (int s = 0; s < 32; ++s) {
            if (s == 0) {
                const u32* h0p = (const u32*)(enc + (size_t)511 * BATCH * HD);
                for (int i = 0; i < 64; ++i) {
                    int idx = tid + i * 512;
                    hlds32[(idx >> 8) * 260 + (idx & 255)] = h0p[idx];
                }
            } else {
                const u32* src = hh + (size_t)(s % 3) * 32768;
                const u32 blo = (s & 1) ? 0xBF80u : 0x3F80u;
                const u32 bhi = (s & 1) ? 0xC040u : 0x4040u;
                const float band = (s & 1) ? -2.0f : 2.0f;
                #pragma unroll
                for (int ch = 0; ch < 4; ++ch) {
                    u32 v[16];
                    #pragma unroll
                    for (int i = 0; i < 16; ++i)
                        v[i] = cld(src + tid + (ch * 16 + i) * 512);
                    for (;;) {
                        u32 bad = 0;
                        #pragma unroll
                        for (int i = 0; i < 16; ++i)
                            bad |= (okw(v[i], blo, bhi) ? 0u : (1u << i));
                        if (!bad) break;
                        __builtin_amdgcn_s_sleep(1);
                        #pragma unroll
                        for (int i = 0; i < 16; ++i)
                            if (bad & (1u << i)) v[i] = cld(src + tid + (ch * 16 + i) * 512);
                    }
                    #pragma unroll
                    for (int i = 0; i < 16; ++i) {
                        int idx = tid + (ch * 16 + i) * 512;
                        float f0 = b2f((u16)(v[i] & 0xFFFF)) - band;
                        float f1 = b2f((u16)(v[i] >> 16)) - band;
                        u32 pk = (__float_as_uint(f0) >> 16) |
                                 (__float_as_uint(f1) & 0xFFFF0000u);
                        hlds32[(idx >> 8) * 260 + (idx & 255)] = pk;
                    }
                }
            }
            __syncthreads();

            f32x4 acc[8];
            #pragma unroll
            for (int mt = 0; mt < 8; ++mt) acc[mt] = (f32x4){0.f, 0.f, 0.f, 0.f};
            #pragma unroll
            for (int ks = 0; ks < 16; ++ks) {
                s16x8 bv = bw[ks];
                #pragma unroll
                for (int mt = 0; mt < 8; ++mt) {
                    s16x8 av = *(const s16x8*)
                        &sm.r.hlds[(mt * 16 + cl) * WPAD + ks * 32 + q * 8];
                    acc[mt] = __builtin_amdgcn_mfma_f32_16x16x32_bf16(av, bv, acc[mt], 0, 0, 0);
                }
            }

            if (s == 0) {
                if (tid < 128) sm.r.xl[tid] = xlast[tid];
            } else if (tid < 128) {
                u32 v = cld(xb + s * 128 + tid);
                float f = __uint_as_float(v);
                while (!(f >= 2.0f && f < 3e38f)) {
                    __builtin_amdgcn_s_sleep(1);
                    v = cld(xb + s * 128 + tid);
                    f = __uint_as_float(v);
                }
                sm.r.xl[tid] = f - 2.0f;
            }
            __syncthreads();

            const int m1 = s + 1;
            u32* dst = hh + (size_t)(m1 % 3) * 32768;
            const float bandw = (m1 & 1) ? -2.0f : 2.0f;
            const int jloc = R + cl;
            const float wihj = sm.r.wihl[jloc];
            const float biaj = sm.r.biasl[jloc];
            #pragma unroll
            for (int mt = 0; mt < 8; ++mt) {
                #pragma unroll
                for (int r4 = 0; r4 < 4; ++r4) {
                    int b = mt * 16 + q * 4 + r4;
                    float hvv = tanh_f(acc[mt][r4] + sm.r.xl[b] * wihj + biaj);
                    u16 bb = f2b(hvv + bandw);
                    u32 nb = (u32)__shfl_down((int)(u32)bb, 1, 64);
                    if (!(cl & 1))
                        cst(dst + b * 256 + ((jbase + jloc) >> 1),
                            (u32)bb | (nb << 16));
                }
            }
            __syncthreads();
        }
    } else {
        // ================= attention workgroup (one batch row) =================
        const int b = wg - 4;
        const float lwt = linW[tid];
        const float lb = linb[0];
        const u16* eb = enc + (size_t)b * HD + lane * 8;  // + t*65536

        // tier 1: 24 t-rows per lane in VGPRs (t = tt*8 + wv, tt in [0,24))
        uint4 ec[24];
        #pragma unroll
        for (int i = 0; i < 24; ++i)
            ec[i] = *(const uint4*)(eb + (size_t)(i * 8 + wv) * 65536);
        // tier 2: 16 t-rows per wave into LDS (tt in [24,40)); wave-private rows
        #pragma unroll
        for (int i = 0; i < 16; ++i) {
            uint4 v = *(const uint4*)(eb + (size_t)((24 + i) * 8 + wv) * 65536);
            *(uint4*)&sm.a.elds[(size_t)(i * 8 + wv) * 512 + lane * 8] = v;
        }

        float m, l, acc[8], h8[8];
        auto proc8 = [&](const uint4* e8) {
            float sp[8];
            #pragma unroll
            for (int i = 0; i < 8; ++i) {
                uint4 e4 = e8[i];
                float d = 0.f;
                d = fmaf(b2f((u16)(e4.x & 0xFFFF)), h8[0], d);
                d = fmaf(b2f((u16)(e4.x >> 16)),    h8[1], d);
                d = fmaf(b2f((u16)(e4.y & 0xFFFF)), h8[2], d);
                d = fmaf(b2f((u16)(e4.y >> 16)),    h8[3], d);
                d = fmaf(b2f((u16)(e4.z & 0xFFFF)), h8[4], d);
                d = fmaf(b2f((u16)(e4.z >> 16)),    h8[5], d);
                d = fmaf(b2f((u16)(e4.w & 0xFFFF)), h8[6], d);
                d = fmaf(b2f((u16)(e4.w >> 16)),    h8[7], d);
                sp[i] = d;
            }
            #pragma unroll
            for (int mk = 1; mk < 64; mk <<= 1) {
                #pragma unroll
                for (int i = 0; i < 8; ++i) sp[i] += __shfl_xor(sp[i], mk, 64);
            }
            float bm = sp[0];
            #pragma unroll
            for (int i = 1; i < 8; ++i) bm = fmaxf(bm, sp[i]);
            float nm = fmaxf(m, bm);
            float sc = __expf(m - nm);
            l *= sc;
            #pragma unroll
            for (int j = 0; j < 8; ++j) acc[j] *= sc;
            #pragma unroll
            for (int i = 0; i < 8; ++i) {
                float p = __expf(sp[i] - nm);
                l += p;
                uint4 e4 = e8[i];
                acc[0] = fmaf(p, b2f((u16)(e4.x & 0xFFFF)), acc[0]);
                acc[1] = fmaf(p, b2f((u16)(e4.x >> 16)),    acc[1]);
                acc[2] = fmaf(p, b2f((u16)(e4.y & 0xFFFF)), acc[2]);
                acc[3] = fmaf(p, b2f((u16)(e4.y >> 16)),    acc[3]);
                acc[4] = fmaf(p, b2f((u16)(e4.z & 0xFFFF)), acc[4]);
                acc[5] = fmaf(p, b2f((u16)(e4.z >> 16)),    acc[5]);
                acc[6] = fmaf(p, b2f((u16)(e4.w & 0xFFFF)), acc[6]);
                acc[7] = fmaf(p, b2f((u16)(e4.w >> 16)),    acc[7]);
            }
            m = nm;
        };

        for (int s = 0; s < 32; ++s) {
            // issue stream block S0 (tt 40..47) before the h-poll
            uint4 s0[8];
            #pragma unroll
            for (int i = 0; i < 8; ++i)
                s0[i] = *(const uint4*)(eb + (size_t)((40 + i) * 8 + wv) * 65536);

            // ---- poll h_{s+1}
            {
                const int m1 = s + 1;
                const u32* src = hh + (size_t)(m1 % 3) * 32768 + b * 256;
                const u32 blo = (m1 & 1) ? 0xBF80u : 0x3F80u;
                const u32 bhi = (m1 & 1) ? 0xC040u : 0x4040u;
                const float band = (m1 & 1) ? -2.0f : 2.0f;
                if (tid < 256) {
                    u32 v = cld(src + tid);
                    while (!okw(v, blo, bhi)) {
                        __builtin_amdgcn_s_sleep(1);
                        v = cld(src + tid);
                    }
                    sm.a.hn[2 * tid]     = b2f((u16)(v & 0xFFFF)) - band;
                    sm.a.hn[2 * tid + 1] = b2f((u16)(v >> 16)) - band;
                }
            }
            __syncthreads();
            #pragma unroll
            for (int i = 0; i < 8; ++i) h8[i] = sm.a.hn[lane * 8 + i];

            m = -1e30f; l = 0.f;
            #pragma unroll
            for (int i = 0; i < 8; ++i) acc[i] = 0.f;

            // register tier (tt 0..23)
            proc8(&ec[0]);
            proc8(&ec[8]);
            proc8(&ec[16]);

            // issue S1 (tt 48..55)
            uint4 s1[8];
            #pragma unroll
            for (int i = 0; i < 8; ++i)
                s1[i] = *(const uint4*)(eb + (size_t)((48 + i) * 8 + wv) * 65536);

            // LDS tier (tt 24..39), wave-private rows
            {
                uint4 e8[8];
                #pragma unroll
                for (int i = 0; i < 8; ++i)
                    e8[i] = *(const uint4*)&sm.a.elds[(size_t)(i * 8 + wv) * 512 + lane * 8];
                proc8(e8);
                #pragma unroll
                for (int i = 0; i < 8; ++i)
                    e8[i] = *(const uint4*)&sm.a.elds[(size_t)((8 + i) * 8 + wv) * 512 + lane * 8];
                proc8(e8);
            }

            // consume S0; issue S2 (tt 56..63); consume S1, S2
            proc8(s0);
            uint4 s2[8];
            #pragma unroll
            for (int i = 0; i < 8; ++i)
                s2[i] = *(const uint4*)(eb + (size_t)((56 + i) * 8 + wv) * 65536);
            proc8(s1);
            proc8(s2);

            if (lane == 0) { sm.a.mw[wv] = m; sm.a.lw[wv] = l; }
            #pragma unroll
            for (int i = 0; i < 8; ++i) sm.a.ctxl[wv * HD + lane * 8 + i] = acc[i];
            __syncthreads();

            // ---- merge waves, project, relu, emit out + x
            float M = sm.a.mw[0];
            #pragma unroll
            for (int i = 1; i < 8; ++i) M = fmaxf(M, sm.a.mw[i]);
            float L = 0.f, aw[8];
            #pragma unroll
            for (int i = 0; i < 8; ++i) {
                aw[i] = __expf(sm.a.mw[i] - M);
                L += aw[i] * sm.a.lw[i];
            }
            float cj = 0.f;
            #pragma unroll
            for (int i = 0; i < 8; ++i) cj = fmaf(aw[i], sm.a.ctxl[i * HD + tid], cj);
            float r = cj * lwt;
            #pragma unroll
            for (int mk = 1; mk < 64; mk <<= 1) r += __shfl_xor(r, mk, 64);
            if (lane == 0) sm.a.red[wv] = r;
            __syncthreads();
            if (tid == 0) {
                float o = (sm.a.red[0] + sm.a.red[1] + sm.a.red[2] + sm.a.red[3] +
                           sm.a.red[4] + sm.a.red[5] + sm.a.red[6] + sm.a.red[7]) / L + lb;
                o = fmaxf(o, 0.f);
                dout[s * BATCH + b] = o;
                if (s < 31)
                    cst(xb + (s + 1) * 128 + b, __float_as_uint(o + 2.0f));
            }
            __syncthreads();
        }
    }
}

// ---------------------------------------------------------------------------
extern "C" void kernel_launch(void* const* d_in, const int* in_sizes, int n_in,
                              void* d_out, int out_size, void* d_ws, size_t ws_size,
                              hipStream_t stream) {
    const float* xseq = (const float*)d_in[0];   // [513,128,1]
    const float* h0   = (const float*)d_in[1];
    const float* c0   = (const float*)d_in[2];
    const float* Wih  = (const float*)d_in[3];   // [2048,1]
    const float* Whh  = (const float*)d_in[4];   // [2048,512]
    const float* bih  = (const float*)d_in[5];
    const float* bhh  = (const float*)d_in[6];
    const float* rWih = (const float*)d_in[7];   // [512,1]
    const float* rWhh = (const float*)d_in[8];   // [512,512]
    const float* rbih = (const float*)d_in[9];
    const float* rbhh = (const float*)d_in[10];
    const float* linW = (const float*)d_in[11];  // [1,512]
    const float* linb = (const float*)d_in[12];
    float* dout = (float*)d_out;                 // [32,128,1]

    // workspace layout (~64.8 MB)
    char* ws = (char*)d_ws;
    u16* enc = (u16*)ws;                         // 64 MB bf16 [t][b][h]
    u32* hbT = (u32*)(ws + 67108864);            // enc ring: 3 x 8 x 4096 u32
    u32* hh  = (u32*)(ws + 67502080);            // dec h ring: 3 x 32768 u32
    u32* xb  = (u32*)(ws + 67895296);            // dec x: 32 x 128 f32

    init_misc<<<128, 256, 0, stream>>>(h0, hbT);
    enc_lstm<<<128, 512, 0, stream>>>(xseq, c0, Wih, Whh, bih, bhh,
                                      (u32*)enc, hbT);
    dec_all<<<132, 512, 0, stream>>>(xseq + 512 * BATCH, enc, rWhh, rWih,
                                     rbih, rbhh, linW, linb, dout, hh, xb);
}